// Round 2
// baseline (952.226 us; speedup 1.0000x reference)
//
#include <hip/hip_runtime.h>

#define D 128
#define KNEG 5
#define BLOCK 256
#define GRPS_PER_BLOCK (BLOCK / 4)

// zero the ws accumulator each call (harness doesn't re-poison between replays)
__global__ void zero_ws_kernel(double* ws) { *ws = 0.0; }

// softplus(z) = max(z,0) + log(1+exp(-|z|)) with fast HW intrinsics.
// exp arg <= 0 so exp in (0,1], log arg in (1,2] — well conditioned.
__device__ __forceinline__ float softplus_fast(float z) {
    return fmaxf(z, 0.0f) + __logf(1.0f + __expf(-fabsf(z)));
}

__global__ __launch_bounds__(BLOCK) void neg_loss_main(
    const float* __restrict__ x,
    const int*   __restrict__ ei,    // [2, E]: src at [0..E), dst at [E..2E)
    const int*   __restrict__ nei,   // [K, E]
    double*      __restrict__ ws,
    int E)
{
    const int l4   = threadIdx.x & 3;                       // lane within 4-lane group
    const int grp  = blockIdx.x * GRPS_PER_BLOCK + (threadIdx.x >> 2);
    const int ngrp = gridDim.x * GRPS_PER_BLOCK;
    const int col0 = l4 * 32;                               // 32 columns per lane

    float local = 0.0f;

    for (int e = grp; e < E; e += ngrp) {
        const int src = ei[e];
        int idx[6];
        idx[0] = ei[E + e];
        #pragma unroll
        for (int k = 0; k < KNEG; ++k) idx[1 + k] = nei[(size_t)E * k + e];

        // load this lane's 32-column slice of x[src] into registers (reused 6x)
        const float4* vp = reinterpret_cast<const float4*>(x + (size_t)src * D + col0);
        float4 v[8];
        #pragma unroll
        for (int j = 0; j < 8; ++j) v[j] = vp[j];

        float a[6];
        #pragma unroll
        for (int n = 0; n < 6; ++n) {
            const float4* up = reinterpret_cast<const float4*>(x + (size_t)idx[n] * D + col0);
            float4 s = make_float4(0.f, 0.f, 0.f, 0.f);   // 4 independent fma chains
            #pragma unroll
            for (int j = 0; j < 8; ++j) {
                const float4 u = up[j];
                s.x = fmaf(v[j].x, u.x, s.x);
                s.y = fmaf(v[j].y, u.y, s.y);
                s.z = fmaf(v[j].z, u.z, s.z);
                s.w = fmaf(v[j].w, u.w, s.w);
            }
            float t = (s.x + s.y) + (s.z + s.w);
            // reduce across the 4-lane group (xor masks 1,2 stay in-group)
            t += __shfl_xor(t, 1);
            t += __shfl_xor(t, 2);
            a[n] = t;   // all 4 lanes now hold the full dot product
        }

        // distribute the 6 softplus terms across the 4 lanes:
        //   lane0: softplus(-a0) [positive logit] + softplus(a4)
        //   lane1: softplus(a1) + softplus(a5)
        //   lane2: softplus(a2);  lane3: softplus(a3)
        const float z0 = (l4 == 0) ? -a[0] : a[l4];
        local += softplus_fast(z0);
        if (l4 < 2) local += softplus_fast(a[4 + l4]);
    }

    // full-wave butterfly reduce (64 lanes)
    #pragma unroll
    for (int off = 32; off > 0; off >>= 1) local += __shfl_xor(local, off);

    __shared__ float sbuf[BLOCK / 64];
    const int wid = threadIdx.x >> 6;
    if ((threadIdx.x & 63) == 0) sbuf[wid] = local;
    __syncthreads();
    if (threadIdx.x == 0) {
        float s = 0.0f;
        #pragma unroll
        for (int i = 0; i < BLOCK / 64; ++i) s += sbuf[i];
        atomicAdd(ws, (double)s);
    }
}

__global__ void finalize_kernel(const double* __restrict__ ws,
                                float* __restrict__ out,
                                double count)
{
    *out = (float)(*ws / count);
}

extern "C" void kernel_launch(void* const* d_in, const int* in_sizes, int n_in,
                              void* d_out, int out_size, void* d_ws, size_t ws_size,
                              hipStream_t stream)
{
    const float* x  = (const float*)d_in[0];
    const int*  ei  = (const int*)d_in[1];
    const int*  nei = (const int*)d_in[2];
    const int E = in_sizes[1] / 2;

    double* ws = (double*)d_ws;
    float* out = (float*)d_out;

    zero_ws_kernel<<<dim3(1), dim3(1), 0, stream>>>(ws);

    const int blocks = 2048;   // grid-stride; ~5 edges per 4-lane group
    neg_loss_main<<<dim3(blocks), dim3(BLOCK), 0, stream>>>(x, ei, nei, ws, E);

    const double count = (double)E * (double)(KNEG + 1);
    finalize_kernel<<<dim3(1), dim3(1), 0, stream>>>(ws, out, count);
}

// Round 3
// 158.154 us; speedup vs baseline: 6.0209x; 6.0209x over previous
//
#include <hip/hip_runtime.h>

#define D 128
#define KNEG 5
#define BLOCK 256

typedef _Float16 h2 __attribute__((ext_vector_type(2)));
typedef _Float16 h8 __attribute__((ext_vector_type(8)));

// ---- helpers ---------------------------------------------------------------

// stable fast softplus: max(z,0) + log(1+exp(-|z|)); exp arg <= 0, log arg in (1,2]
__device__ __forceinline__ float softplus_fast(float z) {
    return fmaxf(z, 0.0f) + __logf(1.0f + __expf(-fabsf(z)));
}

__device__ __forceinline__ float dot2_acc(h2 a, h2 b, float acc) {
#if defined(__has_builtin)
#if __has_builtin(__builtin_amdgcn_fdot2)
    return __builtin_amdgcn_fdot2(a, b, acc, false);
#else
    return fmaf((float)a[0], (float)b[0], fmaf((float)a[1], (float)b[1], acc));
#endif
#else
    return fmaf((float)a[0], (float)b[0], fmaf((float)a[1], (float)b[1], acc));
#endif
}

__device__ __forceinline__ float dot_h8(h8 a, h8 b, float acc) {
    acc = dot2_acc(__builtin_shufflevector(a, a, 0, 1), __builtin_shufflevector(b, b, 0, 1), acc);
    acc = dot2_acc(__builtin_shufflevector(a, a, 2, 3), __builtin_shufflevector(b, b, 2, 3), acc);
    acc = dot2_acc(__builtin_shufflevector(a, a, 4, 5), __builtin_shufflevector(b, b, 4, 5), acc);
    acc = dot2_acc(__builtin_shufflevector(a, a, 6, 7), __builtin_shufflevector(b, b, 6, 7), acc);
    return acc;
}

// ---- kernels ---------------------------------------------------------------

__global__ void zero_ws_kernel(double* ws) { *ws = 0.0; }

// fp32 -> fp16 row compression; 8 elements per thread; also zeroes the accumulator
__global__ __launch_bounds__(BLOCK) void cvt_kernel(const float* __restrict__ x,
                                                    h8* __restrict__ xh,
                                                    double* __restrict__ ws, int n8)
{
    if (blockIdx.x == 0 && threadIdx.x == 0) *ws = 0.0;
    int i = blockIdx.x * BLOCK + threadIdx.x;
    const int stride = gridDim.x * BLOCK;
    for (; i < n8; i += stride) {
        const float4* p = reinterpret_cast<const float4*>(x) + 2 * (size_t)i;
        const float4 f0 = p[0], f1 = p[1];
        h8 o;
        o[0] = (_Float16)f0.x; o[1] = (_Float16)f0.y; o[2] = (_Float16)f0.z; o[3] = (_Float16)f0.w;
        o[4] = (_Float16)f1.x; o[5] = (_Float16)f1.y; o[6] = (_Float16)f1.z; o[7] = (_Float16)f1.w;
        xh[i] = o;
    }
}

// main kernel, fp16 rows: 16 lanes per edge (4 edges/wave), lane holds 8 cols (16 B)
__global__ __launch_bounds__(BLOCK) void neg_loss_f16(
    const h8* __restrict__ xh,      // [N, D/8] h8; row = 256 B
    const int* __restrict__ ei,     // [2, E]
    const int* __restrict__ nei,    // [K, E]
    double* __restrict__ ws, int E)
{
    const int l    = threadIdx.x & 15;
    const int grp  = blockIdx.x * (BLOCK / 16) + (threadIdx.x >> 4);
    const int ngrp = gridDim.x * (BLOCK / 16);

    float local = 0.0f;

    for (int e = grp; e < E; e += ngrp) {
        const int src = ei[e];
        const int i0 = ei[E + e];
        const int i1 = nei[e];
        const int i2 = nei[(size_t)E * 1 + e];
        const int i3 = nei[(size_t)E * 2 + e];
        const int i4 = nei[(size_t)E * 3 + e];
        const int i5 = nei[(size_t)E * 4 + e];

        const h8 vi = xh[(size_t)src * (D / 8) + l];   // this lane's 16 B slice, reused 6x
        const h8 u0 = xh[(size_t)i0 * (D / 8) + l];
        const h8 u1 = xh[(size_t)i1 * (D / 8) + l];
        const h8 u2 = xh[(size_t)i2 * (D / 8) + l];
        const h8 u3 = xh[(size_t)i3 * (D / 8) + l];
        const h8 u4 = xh[(size_t)i4 * (D / 8) + l];
        const h8 u5 = xh[(size_t)i5 * (D / 8) + l];

        float a0 = dot_h8(vi, u0, 0.0f);
        float a1 = dot_h8(vi, u1, 0.0f);
        float a2 = dot_h8(vi, u2, 0.0f);
        float a3 = dot_h8(vi, u3, 0.0f);
        float a4 = dot_h8(vi, u4, 0.0f);
        float a5 = dot_h8(vi, u5, 0.0f);

        // butterfly over the 16-lane group (xor masks <16 stay in-group)
        #pragma unroll
        for (int off = 8; off > 0; off >>= 1) {
            a0 += __shfl_xor(a0, off);
            a1 += __shfl_xor(a1, off);
            a2 += __shfl_xor(a2, off);
            a3 += __shfl_xor(a3, off);
            a4 += __shfl_xor(a4, off);
            a5 += __shfl_xor(a5, off);
        }

        // all lanes hold all 6 dots; lanes 0-5 each take one softplus term.
        // positive logit: softplus(z) - z = softplus(-z); negatives: softplus(z)
        float z = -a0;
        if (l == 1) z = a1;
        else if (l == 2) z = a2;
        else if (l == 3) z = a3;
        else if (l == 4) z = a4;
        else if (l == 5) z = a5;
        if (l < 6) local += softplus_fast(z);
    }

    // full-wave butterfly then block reduce
    #pragma unroll
    for (int off = 32; off > 0; off >>= 1) local += __shfl_xor(local, off);

    __shared__ float sbuf[BLOCK / 64];
    const int wid = threadIdx.x >> 6;
    if ((threadIdx.x & 63) == 0) sbuf[wid] = local;
    __syncthreads();
    if (threadIdx.x == 0) {
        float s = 0.0f;
        #pragma unroll
        for (int i = 0; i < BLOCK / 64; ++i) s += sbuf[i];
        atomicAdd(ws, (double)s);
    }
}

// fallback, fp32 rows (round-1 gather layout + distributed fast softplus):
// 32 lanes per edge, lane holds 4 cols (16 B)
__global__ __launch_bounds__(BLOCK) void neg_loss_f32(
    const float* __restrict__ x,
    const int* __restrict__ ei,
    const int* __restrict__ nei,
    double* __restrict__ ws, int E)
{
    const int l    = threadIdx.x & 31;
    const int grp  = blockIdx.x * (BLOCK / 32) + (threadIdx.x >> 5);
    const int ngrp = gridDim.x * (BLOCK / 32);
    const int colb = l * 4;

    float local = 0.0f;

    for (int e = grp; e < E; e += ngrp) {
        const int src = ei[e];
        int idx0 = ei[E + e];
        int idx1 = nei[e];
        int idx2 = nei[(size_t)E * 1 + e];
        int idx3 = nei[(size_t)E * 2 + e];
        int idx4 = nei[(size_t)E * 3 + e];
        int idx5 = nei[(size_t)E * 4 + e];

        const float4 vi = *reinterpret_cast<const float4*>(x + (size_t)src * D + colb);
        float a0, a1, a2, a3, a4, a5;
        {
            const float4 u = *reinterpret_cast<const float4*>(x + (size_t)idx0 * D + colb);
            a0 = fmaf(vi.x, u.x, fmaf(vi.y, u.y, fmaf(vi.z, u.z, vi.w * u.w)));
        }
        {
            const float4 u = *reinterpret_cast<const float4*>(x + (size_t)idx1 * D + colb);
            a1 = fmaf(vi.x, u.x, fmaf(vi.y, u.y, fmaf(vi.z, u.z, vi.w * u.w)));
        }
        {
            const float4 u = *reinterpret_cast<const float4*>(x + (size_t)idx2 * D + colb);
            a2 = fmaf(vi.x, u.x, fmaf(vi.y, u.y, fmaf(vi.z, u.z, vi.w * u.w)));
        }
        {
            const float4 u = *reinterpret_cast<const float4*>(x + (size_t)idx3 * D + colb);
            a3 = fmaf(vi.x, u.x, fmaf(vi.y, u.y, fmaf(vi.z, u.z, vi.w * u.w)));
        }
        {
            const float4 u = *reinterpret_cast<const float4*>(x + (size_t)idx4 * D + colb);
            a4 = fmaf(vi.x, u.x, fmaf(vi.y, u.y, fmaf(vi.z, u.z, vi.w * u.w)));
        }
        {
            const float4 u = *reinterpret_cast<const float4*>(x + (size_t)idx5 * D + colb);
            a5 = fmaf(vi.x, u.x, fmaf(vi.y, u.y, fmaf(vi.z, u.z, vi.w * u.w)));
        }

        #pragma unroll
        for (int off = 16; off > 0; off >>= 1) {
            a0 += __shfl_xor(a0, off);
            a1 += __shfl_xor(a1, off);
            a2 += __shfl_xor(a2, off);
            a3 += __shfl_xor(a3, off);
            a4 += __shfl_xor(a4, off);
            a5 += __shfl_xor(a5, off);
        }

        float z = -a0;
        if (l == 1) z = a1;
        else if (l == 2) z = a2;
        else if (l == 3) z = a3;
        else if (l == 4) z = a4;
        else if (l == 5) z = a5;
        if (l < 6) local += softplus_fast(z);
    }

    #pragma unroll
    for (int off = 32; off > 0; off >>= 1) local += __shfl_xor(local, off);

    __shared__ float sbuf[BLOCK / 64];
    const int wid = threadIdx.x >> 6;
    if ((threadIdx.x & 63) == 0) sbuf[wid] = local;
    __syncthreads();
    if (threadIdx.x == 0) {
        float s = 0.0f;
        #pragma unroll
        for (int i = 0; i < BLOCK / 64; ++i) s += sbuf[i];
        atomicAdd(ws, (double)s);
    }
}

__global__ void finalize_kernel(const double* __restrict__ ws,
                                float* __restrict__ out, double count)
{
    *out = (float)(*ws / count);
}

// ---- launch ----------------------------------------------------------------

extern "C" void kernel_launch(void* const* d_in, const int* in_sizes, int n_in,
                              void* d_out, int out_size, void* d_ws, size_t ws_size,
                              hipStream_t stream)
{
    const float* x  = (const float*)d_in[0];
    const int*  ei  = (const int*)d_in[1];
    const int*  nei = (const int*)d_in[2];
    const int E  = in_sizes[1] / 2;
    const int ND = in_sizes[0];          // N*D elements of x

    double* ws = (double*)d_ws;
    float* out = (float*)d_out;

    const size_t need = 256 + (size_t)ND * sizeof(_Float16);
    if (ws_size >= need) {
        h8* xh = (h8*)((char*)d_ws + 256);
        cvt_kernel<<<dim3(1024), dim3(BLOCK), 0, stream>>>(x, xh, ws, ND / 8);
        neg_loss_f16<<<dim3(2048), dim3(BLOCK), 0, stream>>>(xh, ei, nei, ws, E);
    } else {
        zero_ws_kernel<<<dim3(1), dim3(1), 0, stream>>>(ws);
        neg_loss_f32<<<dim3(2048), dim3(BLOCK), 0, stream>>>(x, ei, nei, ws, E);
    }

    const double count = (double)E * (double)(KNEG + 1);
    finalize_kernel<<<dim3(1), dim3(1), 0, stream>>>(ws, out, count);
}

// Round 4
// 155.234 us; speedup vs baseline: 6.1341x; 1.0188x over previous
//
#include <hip/hip_runtime.h>

#define D 128
#define KNEG 5
#define BLOCK 256
#define RPW 16   // h8 chunks per row (D/8)

typedef _Float16 h2 __attribute__((ext_vector_type(2)));
typedef _Float16 h8 __attribute__((ext_vector_type(8)));

// ---- helpers ---------------------------------------------------------------

// stable fast softplus: max(z,0) + log(1+exp(-|z|)); exp arg <= 0, log arg in (1,2]
__device__ __forceinline__ float softplus_fast(float z) {
    return fmaxf(z, 0.0f) + __logf(1.0f + __expf(-fabsf(z)));
}

__device__ __forceinline__ float dot2_acc(h2 a, h2 b, float acc) {
#if defined(__has_builtin)
#if __has_builtin(__builtin_amdgcn_fdot2)
    return __builtin_amdgcn_fdot2(a, b, acc, false);
#else
    return fmaf((float)a[0], (float)b[0], fmaf((float)a[1], (float)b[1], acc));
#endif
#else
    return fmaf((float)a[0], (float)b[0], fmaf((float)a[1], (float)b[1], acc));
#endif
}

__device__ __forceinline__ float dot_h8(h8 a, h8 b) {
    float acc = 0.0f;
    acc = dot2_acc(__builtin_shufflevector(a, a, 0, 1), __builtin_shufflevector(b, b, 0, 1), acc);
    acc = dot2_acc(__builtin_shufflevector(a, a, 2, 3), __builtin_shufflevector(b, b, 2, 3), acc);
    acc = dot2_acc(__builtin_shufflevector(a, a, 4, 5), __builtin_shufflevector(b, b, 4, 5), acc);
    acc = dot2_acc(__builtin_shufflevector(a, a, 6, 7), __builtin_shufflevector(b, b, 6, 7), acc);
    return acc;
}

// ---- kernels ---------------------------------------------------------------

__global__ void zero_ws_kernel(double* ws) { *ws = 0.0; }

// fp32 -> fp16 row compression; 8 elements per thread; also zeroes the accumulator
__global__ __launch_bounds__(BLOCK) void cvt_kernel(const float* __restrict__ x,
                                                    h8* __restrict__ xh,
                                                    double* __restrict__ ws, int n8)
{
    if (blockIdx.x == 0 && threadIdx.x == 0) *ws = 0.0;
    int i = blockIdx.x * BLOCK + threadIdx.x;
    const int stride = gridDim.x * BLOCK;
    for (; i < n8; i += stride) {
        const float4* p = reinterpret_cast<const float4*>(x) + 2 * (size_t)i;
        const float4 f0 = p[0], f1 = p[1];
        h8 o;
        o[0] = (_Float16)f0.x; o[1] = (_Float16)f0.y; o[2] = (_Float16)f0.z; o[3] = (_Float16)f0.w;
        o[4] = (_Float16)f1.x; o[5] = (_Float16)f1.y; o[6] = (_Float16)f1.z; o[7] = (_Float16)f1.w;
        xh[i] = o;
    }
}

// main kernel: 16 lanes per edge-pair slot, 2 edges per iteration, index prefetch.
__global__ __launch_bounds__(BLOCK) void neg_loss_f16(
    const h8* __restrict__ xh,      // [N, 16] h8; row = 256 B
    const int* __restrict__ ei,     // [2, E]
    const int* __restrict__ nei,    // [K, E]
    double* __restrict__ ws, int E)
{
    const int l    = threadIdx.x & 15;
    const int grp  = blockIdx.x * (BLOCK / 16) + (threadIdx.x >> 4);
    const int ngrp = gridDim.x * (BLOCK / 16);
    const int stride = 2 * ngrp;

    float local = 0.0f;

    int e0 = 2 * grp;
    if (e0 < E - 1) {
        // prologue: indices for the first pair (edges e0, e0+1) as int2 loads
        int2 sP  = *reinterpret_cast<const int2*>(ei + e0);
        int2 dP  = *reinterpret_cast<const int2*>(ei + (size_t)E + e0);
        int2 n0P = *reinterpret_cast<const int2*>(nei + e0);
        int2 n1P = *reinterpret_cast<const int2*>(nei + (size_t)E * 1 + e0);
        int2 n2P = *reinterpret_cast<const int2*>(nei + (size_t)E * 2 + e0);
        int2 n3P = *reinterpret_cast<const int2*>(nei + (size_t)E * 3 + e0);
        int2 n4P = *reinterpret_cast<const int2*>(nei + (size_t)E * 4 + e0);

        while (e0 < E - 1) {
            const int2 sC = sP, dC = dP, n0C = n0P, n1C = n1P, n2C = n2P, n3C = n3P, n4C = n4P;

            // issue all 14 row loads for the current pair up front
            const h8 vA  = xh[(size_t)sC.x  * RPW + l];
            const h8 vB  = xh[(size_t)sC.y  * RPW + l];
            const h8 uA0 = xh[(size_t)dC.x  * RPW + l];
            const h8 uB0 = xh[(size_t)dC.y  * RPW + l];
            const h8 uA1 = xh[(size_t)n0C.x * RPW + l];
            const h8 uB1 = xh[(size_t)n0C.y * RPW + l];
            const h8 uA2 = xh[(size_t)n1C.x * RPW + l];
            const h8 uB2 = xh[(size_t)n1C.y * RPW + l];
            const h8 uA3 = xh[(size_t)n2C.x * RPW + l];
            const h8 uB3 = xh[(size_t)n2C.y * RPW + l];
            const h8 uA4 = xh[(size_t)n3C.x * RPW + l];
            const h8 uB4 = xh[(size_t)n3C.y * RPW + l];
            const h8 uA5 = xh[(size_t)n4C.x * RPW + l];
            const h8 uB5 = xh[(size_t)n4C.y * RPW + l];

            // prefetch next pair's indices (clamped; unused garbage if last iter)
            const int en = e0 + stride;
            const int ep = (en < E - 1) ? en : e0;
            sP  = *reinterpret_cast<const int2*>(ei + ep);
            dP  = *reinterpret_cast<const int2*>(ei + (size_t)E + ep);
            n0P = *reinterpret_cast<const int2*>(nei + ep);
            n1P = *reinterpret_cast<const int2*>(nei + (size_t)E * 1 + ep);
            n2P = *reinterpret_cast<const int2*>(nei + (size_t)E * 2 + ep);
            n3P = *reinterpret_cast<const int2*>(nei + (size_t)E * 3 + ep);
            n4P = *reinterpret_cast<const int2*>(nei + (size_t)E * 4 + ep);

            // 12 dot partials (this lane's 8-column slice)
            float aA0 = dot_h8(vA, uA0);
            float aA1 = dot_h8(vA, uA1);
            float aA2 = dot_h8(vA, uA2);
            float aA3 = dot_h8(vA, uA3);
            float aA4 = dot_h8(vA, uA4);
            float aA5 = dot_h8(vA, uA5);
            float aB0 = dot_h8(vB, uB0);
            float aB1 = dot_h8(vB, uB1);
            float aB2 = dot_h8(vB, uB2);
            float aB3 = dot_h8(vB, uB3);
            float aB4 = dot_h8(vB, uB4);
            float aB5 = dot_h8(vB, uB5);

            // butterfly over the 16-lane group
            #pragma unroll
            for (int off = 8; off > 0; off >>= 1) {
                aA0 += __shfl_xor(aA0, off);
                aA1 += __shfl_xor(aA1, off);
                aA2 += __shfl_xor(aA2, off);
                aA3 += __shfl_xor(aA3, off);
                aA4 += __shfl_xor(aA4, off);
                aA5 += __shfl_xor(aA5, off);
                aB0 += __shfl_xor(aB0, off);
                aB1 += __shfl_xor(aB1, off);
                aB2 += __shfl_xor(aB2, off);
                aB3 += __shfl_xor(aB3, off);
                aB4 += __shfl_xor(aB4, off);
                aB5 += __shfl_xor(aB5, off);
            }

            // single softplus stream: lanes 0-5 take edge A's 6 terms,
            // lanes 8-13 take edge B's. positive logit uses softplus(-z).
            const int t = l & 7;
            const bool hiB = (l >= 8);
            float z = hiB ? -aB0 : -aA0;
            if (t == 1) z = hiB ? aB1 : aA1;
            else if (t == 2) z = hiB ? aB2 : aA2;
            else if (t == 3) z = hiB ? aB3 : aA3;
            else if (t == 4) z = hiB ? aB4 : aA4;
            else if (t == 5) z = hiB ? aB5 : aA5;
            if (t < 6) local += softplus_fast(z);

            e0 = en;
        }
    }

    // full-wave butterfly then block reduce
    #pragma unroll
    for (int off = 32; off > 0; off >>= 1) local += __shfl_xor(local, off);

    __shared__ float sbuf[BLOCK / 64];
    const int wid = threadIdx.x >> 6;
    if ((threadIdx.x & 63) == 0) sbuf[wid] = local;
    __syncthreads();
    if (threadIdx.x == 0) {
        float s = 0.0f;
        #pragma unroll
        for (int i = 0; i < BLOCK / 64; ++i) s += sbuf[i];
        atomicAdd(ws, (double)s);
    }
}

// fallback, fp32 rows (if ws too small for the fp16 copy)
__global__ __launch_bounds__(BLOCK) void neg_loss_f32(
    const float* __restrict__ x,
    const int* __restrict__ ei,
    const int* __restrict__ nei,
    double* __restrict__ ws, int E)
{
    const int l    = threadIdx.x & 31;
    const int grp  = blockIdx.x * (BLOCK / 32) + (threadIdx.x >> 5);
    const int ngrp = gridDim.x * (BLOCK / 32);
    const int colb = l * 4;

    float local = 0.0f;

    for (int e = grp; e < E; e += ngrp) {
        const int src = ei[e];
        int idx0 = ei[E + e];
        int idx1 = nei[e];
        int idx2 = nei[(size_t)E * 1 + e];
        int idx3 = nei[(size_t)E * 2 + e];
        int idx4 = nei[(size_t)E * 3 + e];
        int idx5 = nei[(size_t)E * 4 + e];

        const float4 vi = *reinterpret_cast<const float4*>(x + (size_t)src * D + colb);
        float a[6];
        const int idx[6] = {idx0, idx1, idx2, idx3, idx4, idx5};
        #pragma unroll
        for (int n = 0; n < 6; ++n) {
            const float4 u = *reinterpret_cast<const float4*>(x + (size_t)idx[n] * D + colb);
            a[n] = fmaf(vi.x, u.x, fmaf(vi.y, u.y, fmaf(vi.z, u.z, vi.w * u.w)));
        }

        #pragma unroll
        for (int off = 16; off > 0; off >>= 1) {
            #pragma unroll
            for (int n = 0; n < 6; ++n) a[n] += __shfl_xor(a[n], off);
        }

        float z = -a[0];
        if (l == 1) z = a[1];
        else if (l == 2) z = a[2];
        else if (l == 3) z = a[3];
        else if (l == 4) z = a[4];
        else if (l == 5) z = a[5];
        if (l < 6) local += softplus_fast(z);
    }

    #pragma unroll
    for (int off = 32; off > 0; off >>= 1) local += __shfl_xor(local, off);

    __shared__ float sbuf[BLOCK / 64];
    const int wid = threadIdx.x >> 6;
    if ((threadIdx.x & 63) == 0) sbuf[wid] = local;
    __syncthreads();
    if (threadIdx.x == 0) {
        float s = 0.0f;
        #pragma unroll
        for (int i = 0; i < BLOCK / 64; ++i) s += sbuf[i];
        atomicAdd(ws, (double)s);
    }
}

__global__ void finalize_kernel(const double* __restrict__ ws,
                                float* __restrict__ out, double count)
{
    *out = (float)(*ws / count);
}

// ---- launch ----------------------------------------------------------------

extern "C" void kernel_launch(void* const* d_in, const int* in_sizes, int n_in,
                              void* d_out, int out_size, void* d_ws, size_t ws_size,
                              hipStream_t stream)
{
    const float* x  = (const float*)d_in[0];
    const int*  ei  = (const int*)d_in[1];
    const int*  nei = (const int*)d_in[2];
    const int E  = in_sizes[1] / 2;
    const int ND = in_sizes[0];          // N*D elements of x

    double* ws = (double*)d_ws;
    float* out = (float*)d_out;

    const size_t need = 256 + (size_t)ND * sizeof(_Float16);
    // fp16 path requires even E (pairwise main loop); E=640000 here.
    if (ws_size >= need && (E % 2) == 0) {
        h8* xh = (h8*)((char*)d_ws + 256);
        cvt_kernel<<<dim3(1024), dim3(BLOCK), 0, stream>>>(x, xh, ws, ND / 8);
        neg_loss_f16<<<dim3(2048), dim3(BLOCK), 0, stream>>>(xh, ei, nei, ws, E);
    } else {
        zero_ws_kernel<<<dim3(1), dim3(1), 0, stream>>>(ws);
        neg_loss_f32<<<dim3(2048), dim3(BLOCK), 0, stream>>>(x, ei, nei, ws, E);
    }

    const double count = (double)E * (double)(KNEG + 1);
    finalize_kernel<<<dim3(1), dim3(1), 0, stream>>>(ws, out, count);
}